// Round 11
// baseline (365.268 us; speedup 1.0000x reference)
//
#include <hip/hip_runtime.h>
#include <hip/hip_bf16.h>

// NestedFeedForward: x[16384,1024] fp32, w1[4096,1024], b1[4096], w2[1024,4096],
// b2[1024], token_mask[16384] in [0,4).   d(t) = 128 << mask[t]
//   h = gelu( mask_in(x) @ w1^T + b1 )   (hidden always full 4096)
//   y = mask_out( h @ w2^T + b2 )
// Round 15: 256x256 gemm1 closed out (3x spill-confounded, VGPR clamp won).
// Revert gemm1 to the clean R10/R6 128x128 2-phase kernel (102us, 631 TF =
// structural ceiling). New lever on gemm2 only: 128x256 tile, 512 thr,
// 8 waves 2Mx4N -> wave tile stays 64x64 (acc[4][4]=64 VGPR, spill-proof),
// 256 MFMA per barrier-pair (2x), staged A-bytes per FLOP halved, vmcnt(6).

typedef __bf16 bf16x8 __attribute__((ext_vector_type(8)));
typedef float f32x4 __attribute__((ext_vector_type(4)));

#define M_TOK   16384
#define DIM     1024
#define HID     4096

// meta (ints at ws+0): [40..47] per-XCD compute count T_k, [64..191] kmax per
// 128-row block (also source of gemm2 colblock count), [256..767] gemm2 map
// (8 XCD chunks x 64: strip*4+colblk256), [2560..18943] rowtok.
#define META_TK    40
#define META_BLK   64
#define META_MAP   256
#define META_RT    2560

__device__ inline unsigned int pk_bf16(float a, float b) {
  unsigned int r;
  asm("v_cvt_pk_bf16_f32 %0, %1, %2" : "=v"(r) : "v"(a), "v"(b));
  return r;
}

// tanh-form gelu: v * rcp(1 + exp2(-(c1*v + c2*v^3))), c1 = 2*0.79788456*log2e
// max |delta| vs erf-gelu ~1e-3, below the bf16 h-storage error.
__device__ inline float gelu_f(float v) {
  float v2 = v * v;
  float w = v * fmaf(0.10294324f, v2, 2.30220830f);
  float e = __builtin_amdgcn_exp2f(-w);
  return v * __builtin_amdgcn_rcpf(1.0f + e);
}

__device__ inline void async_copy16(const void* g, void* s) {
  __builtin_amdgcn_global_load_lds(
      (const __attribute__((address_space(1))) unsigned int*)g,
      (__attribute__((address_space(3))) unsigned int*)s,
      16, 0, 0);
}

// Stage a ROWS x 64-col bf16 tile into LDS with XOR chunk swizzle (2-way
// aliasing on the b128 readbacks = free, m136).
template<int ROWS, int LDK, int THREADS>
__device__ inline void stage_tile(const unsigned short* __restrict__ g,
                                  int row0, int k0, char* lds) {
  const char* gbase = (const char*)g;
  int tid = threadIdx.x;
#pragma unroll
  for (int i = 0; i < ROWS * 8 / THREADS; ++i) {
    int q = i * THREADS + tid;      // ROWS*8 chunks of 16B
    int r = q >> 3;                 // tile row
    int c = q & 7;                  // LDS chunk within row
    int gc = c ^ (r & 7);           // swizzled source chunk
    const void* gp = gbase + ((size_t)(row0 + r) * LDK + (size_t)k0 + gc * 8) * 2;
    async_copy16(gp, lds + (size_t)q * 16);
  }
}

// -------- fused: block 0 = sort + metadata; blocks 1.. = w1/w2 -> bf16 -----
__global__ __launch_bounds__(1024) void sortw_kernel(
    const int* __restrict__ tm,
    const float* __restrict__ w1,
    const float* __restrict__ w2,
    int* __restrict__ meta,
    unsigned short* __restrict__ w1b,
    unsigned short* __restrict__ w2b) {
  int tid = threadIdx.x;
  if (blockIdx.x != 0) {
    // weight conversion: independent of the sort, fills the idle CUs
    size_t i = (size_t)(blockIdx.x - 1) * 4096 + tid * 4;   // 0 .. 8388607
    const float* src;
    unsigned short* dst;
    if (i < (size_t)HID * DIM) { src = w1; dst = w1b; }
    else { src = w2 - (size_t)HID * DIM; dst = w2b - (size_t)HID * DIM; }
    float4 v = *(const float4*)(src + i);
    uint2 o;
    o.x = pk_bf16(v.x, v.y);
    o.y = pk_bf16(v.z, v.w);
    *(uint2*)(dst + i) = o;
    return;
  }

  // ---------------- block 0: counting sort of 16384 tokens ----------------
  __shared__ unsigned short rt[16384];      // 32 KB sorted (t | e<<14) u16
  __shared__ unsigned int w01[16], w23[16]; // per-wave packed count totals
  __shared__ int sbase[4];
  __shared__ int cb[128];
  int lane = tid & 63, wv = tid >> 6;

  int c0 = 0, c1 = 0, c2 = 0, c3 = 0;
  unsigned int epack = 0;
  int4 tv[4];
#pragma unroll
  for (int j = 0; j < 4; ++j)
    tv[j] = *(const int4*)(tm + tid * 16 + j * 4);
#pragma unroll
  for (int j = 0; j < 4; ++j) {
    int e;
    e = tv[j].x; epack |= (unsigned)e << (2 * (4 * j + 0)); c0 += (e == 0); c1 += (e == 1); c2 += (e == 2); c3 += (e == 3);
    e = tv[j].y; epack |= (unsigned)e << (2 * (4 * j + 1)); c0 += (e == 0); c1 += (e == 1); c2 += (e == 2); c3 += (e == 3);
    e = tv[j].z; epack |= (unsigned)e << (2 * (4 * j + 2)); c0 += (e == 0); c1 += (e == 1); c2 += (e == 2); c3 += (e == 3);
    e = tv[j].w; epack |= (unsigned)e << (2 * (4 * j + 3)); c0 += (e == 0); c1 += (e == 1); c2 += (e == 2); c3 += (e == 3);
  }
  // hierarchical exclusive scan of (c0,c1) and (c2,c3), 16-bit packed:
  // intra-wave max 64*16=1024, grand total max 16384 -- both fit 16 bits.
  unsigned int p01 = (unsigned)c0 | ((unsigned)c1 << 16);
  unsigned int p23 = (unsigned)c2 | ((unsigned)c3 << 16);
  unsigned int i01 = p01, i23 = p23;
#pragma unroll
  for (int s = 1; s < 64; s <<= 1) {
    unsigned int t0 = __shfl_up(i01, s, 64);
    unsigned int t1 = __shfl_up(i23, s, 64);
    if (lane >= s) { i01 += t0; i23 += t1; }
  }
  if (lane == 63) { w01[wv] = i01; w23[wv] = i23; }
  unsigned int e01 = i01 - p01, e23 = i23 - p23;   // lane-exclusive prefixes
  __syncthreads();
  if (tid < 16) {
    unsigned int a = w01[tid], b = w23[tid];
    unsigned int ia = a, ib = b;
#pragma unroll
    for (int s = 1; s < 16; s <<= 1) {
      unsigned int t0 = __shfl_up(ia, s, 64);
      unsigned int t1 = __shfl_up(ib, s, 64);
      if (tid >= s) { ia += t0; ib += t1; }
    }
    w01[tid] = ia - a;                       // exclusive wave offsets
    w23[tid] = ib - b;
    if (tid == 15) {
      int t0 = (int)(ia & 0xFFFF), t1 = (int)(ia >> 16), t2 = (int)(ib & 0xFFFF);
      sbase[0] = 0; sbase[1] = t0; sbase[2] = t0 + t1; sbase[3] = t0 + t1 + t2;
    }
  }
  __syncthreads();
  int off0 = sbase[0] + (int)((w01[wv] & 0xFFFF) + (e01 & 0xFFFF));
  int off1 = sbase[1] + (int)((w01[wv] >> 16) + (e01 >> 16));
  int off2 = sbase[2] + (int)((w23[wv] & 0xFFFF) + (e23 & 0xFFFF));
  int off3 = sbase[3] + (int)((w23[wv] >> 16) + (e23 >> 16));
#pragma unroll
  for (int j = 0; j < 16; ++j) {
    int e = (epack >> (2 * j)) & 3;
    int t = tid * 16 + j;
    int pos = (e == 0) ? off0++ : (e == 1) ? off1++ : (e == 2) ? off2++ : off3++;
    rt[pos] = (unsigned short)(t | (e << 14));     // LDS scatter, not global
  }
  __syncthreads();

  // 128-row strip metadata: gemm1 kmax + gemm2 256-col colblock count
  if (tid < 128) {
    int last = tid * 128 + 127;
    int e = (last >= sbase[1]) + (last >= sbase[2]) + (last >= sbase[3]);
    meta[META_BLK + tid] = 128 << e;
    cb[tid] = (e < 2) ? 1 : (1 << (e - 1));   // dout/256 rounded up: 1,1,2,4
  }
  __syncthreads();
  // per-XCD gemm2 map: XCD k owns strips {s : s%8==k} (16 strips, balanced
  // since strips stride uniformly across the sorted expert bands). Compute
  // blocks first, zeros after, threshold T_k. Entry = strip*4 + colblk256.
  if (tid < 8) {
    int k = tid;
    int* map = meta + META_MAP + k * 64;
    int Tk = 0;
    for (int j = 0; j < 16; ++j) Tk += cb[k + 8 * j];
    meta[META_TK + k] = Tk;
    int pos = 0, zpos = Tk;
    for (int j = 0; j < 16; ++j) {
      int s = k + 8 * j;
      int n = cb[s];
      for (int c = 0; c < n; ++c) map[pos++] = s * 4 + c;
      for (int c = n; c < 4; ++c) map[zpos++] = s * 4 + c;
    }
  }
  // coalesced rowtok dump (u16 -> int)
  int* rowtok = meta + META_RT;
#pragma unroll
  for (int j = 0; j < 16; ++j)
    rowtok[j * 1024 + tid] = (int)rt[j * 1024 + tid];
}

// ---------------- prep: cvt_x (permuted gather) -> bf16 --------------------
// Partial IO: read x only d < din, write xb only d < kmax(128-block); gemm1
// never touches A beyond kmax so the padding bytes were pure HBM waste.
__global__ void prepx_kernel(const float* __restrict__ x,
                             const int* __restrict__ meta,
                             unsigned short* __restrict__ xb) {
  int b = blockIdx.x;
  int tid = threadIdx.x;
  int mt = meta[META_RT + b];
  int t = mt & 0x3FFF;
  int din = 128 << (mt >> 14);
  int kb = meta[META_BLK + (b >> 7)];       // kmax >= din (sorted rows)
  int d = tid * 4;
  if (d < kb) {
    uint2 o; o.x = 0; o.y = 0;
    if (d < din) {                          // din multiple of 128: uniform
      float4 v = *(const float4*)(x + (size_t)t * DIM + d);
      o.x = pk_bf16(v.x, v.y);
      o.y = pk_bf16(v.z, v.w);
    }
    *(uint2*)(xb + (size_t)b * DIM + d) = o;
  }
}

// ---- GEMM1: hb[pos,f] = gelu( xb[pos,:] . w1b[f,:] + b1[f] ), bf16 out ----
// R6-verified: 128x128, flat grid high-K-first, dbuf + counted vmcnt(8).
__global__ __launch_bounds__(256) void gemm1_kernel(
    const unsigned short* __restrict__ A,   // xb [16384,1024] bf16 (permuted)
    const unsigned short* __restrict__ B,   // w1b [4096,1024] bf16
    const float* __restrict__ bias,         // b1 [4096]
    const int* __restrict__ meta,
    unsigned short* __restrict__ H)         // hb [16384,4096] bf16 (permuted)
{
  constexpr int K = DIM, N = HID;
  __shared__ char smem[65536];              // 2 x (As 16K + Bs 16K)
  int tid = threadIdx.x;
  int lane = tid & 63, quad = lane >> 4, l15 = lane & 15;
  int wave = tid >> 6, wm = wave & 1, wn = wave >> 1;
  int rowblk = 127 - (blockIdx.x >> 5);
  int row0 = rowblk * 128, col0 = (blockIdx.x & 31) * 128;
  int kmax = meta[META_BLK + rowblk];

  int chb = (quad ^ (l15 & 7)) << 4;        // staging swizzle base

  f32x4 acc[4][4] = {};

  stage_tile<128, K, 256>(A, row0, 0, smem);
  stage_tile<128, K, 256>(B, col0, 0, smem + 16384);

  int nt = kmax >> 6;
  for (int t = 0; t < nt; ++t) {
    char* buf = smem + ((t & 1) << 15);
    if (t + 1 < nt) {                       // prefetch into the other buffer
      char* nbuf = smem + (((t + 1) & 1) << 15);
      int kn = (t + 1) << 6;
      stage_tile<128, K, 256>(A, row0, kn, nbuf);
      stage_tile<128, K, 256>(B, col0, kn, nbuf + 16384);
      asm volatile("s_waitcnt vmcnt(8)" ::: "memory");   // tile t done; t+1 in flight
    } else {
      asm volatile("s_waitcnt vmcnt(0)" ::: "memory");
    }
    __builtin_amdgcn_s_barrier();           // all waves' tile-t LDS writes visible
    char* As = buf;
    char* Bs = buf + 16384;
#pragma unroll
    for (int kk = 0; kk < 2; ++kk) {
      int xo = chb ^ (kk << 6);
      bf16x8 af[4], bg[4];
#pragma unroll
      for (int mt = 0; mt < 4; ++mt)
        af[mt] = *(const bf16x8*)(As + (wm * 64 + mt * 16 + l15) * 128 + xo);
#pragma unroll
      for (int nt2 = 0; nt2 < 4; ++nt2)
        bg[nt2] = *(const bf16x8*)(Bs + (wn * 64 + nt2 * 16 + l15) * 128 + xo);
#pragma unroll
      for (int mt = 0; mt < 4; ++mt)
#pragma unroll
        for (int nt2 = 0; nt2 < 4; ++nt2)
          acc[mt][nt2] = __builtin_amdgcn_mfma_f32_16x16x32_bf16(
              bg[nt2], af[mt], acc[mt][nt2], 0, 0, 0);   // swapped: rows=f
    }
    __builtin_amdgcn_s_barrier();           // reads of buf[t] done before t+2 overwrites
  }

  // Swapped epilogue: lane holds f = f0 + r (r=0..3 contig), t per mt.
  int t_base = row0 + wm * 64;
  int f_base = col0 + wn * 64;
#pragma unroll
  for (int nt2 = 0; nt2 < 4; ++nt2) {
    int f0 = f_base + nt2 * 16 + quad * 4;
    float4 bv = *(const float4*)(bias + f0);
#pragma unroll
    for (int mt = 0; mt < 4; ++mt) {
      int t = t_base + mt * 16 + l15;
      float v0 = gelu_f(acc[mt][nt2][0] + bv.x);
      float v1 = gelu_f(acc[mt][nt2][1] + bv.y);
      float v2 = gelu_f(acc[mt][nt2][2] + bv.z);
      float v3 = gelu_f(acc[mt][nt2][3] + bv.w);
      uint2 p;
      p.x = pk_bf16(v0, v1);
      p.y = pk_bf16(v2, v3);
      *(uint2*)(H + (size_t)t * N + f0) = p;
    }
  }
}

// ---- GEMM2: 128x256 tiles, 512 thr, 8 waves (2Mx4N, wave tile 64x64) ----
// XCD-chunked: XCD k (= blockIdx&7) walks its own 64-entry map chunk in
// order -> same-strip colblocks consecutive on one XCD, hb A-panels L2-hot.
// dbuf + counted vmcnt(6) (2 A + 4 B loads/thread/tile). acc[4][4]=64 VGPR.
__global__ __launch_bounds__(512, 2) void gemm2_kernel(
    const unsigned short* __restrict__ A,   // hb [16384,4096] bf16 (permuted)
    const unsigned short* __restrict__ B,   // w2b [1024,4096] bf16
    const float* __restrict__ bias,         // b2 [1024]
    const int* __restrict__ meta,
    float* __restrict__ out)                // [16384,1024] fp32
{
  constexpr int K = HID, N = DIM;
  int Bk = blockIdx.x & 7, ord = blockIdx.x >> 3;   // grid 512 -> ord < 64
  int Tk = meta[META_TK + Bk];
  int mp = meta[META_MAP + Bk * 64 + ord];
  int row0 = (mp >> 2) * 128, col0 = (mp & 3) * 256;
  const int* rowtok = meta + META_RT;
  int tid = threadIdx.x;

  if (ord >= Tk) {
    // every row in this strip has dout <= col0: coalesced zeros (128x256)
    float4 z = make_float4(0.f, 0.f, 0.f, 0.f);
#pragma unroll
    for (int i = 0; i < 16; ++i) {
      int idx = i * 512 + tid;              // 8192 float4 = 128x256 tile
      int r = idx >> 6;
      int col = (idx & 63) * 4;
      int t = rowtok[row0 + r] & 0x3FFF;
      *(float4*)(out + (size_t)t * N + col0 + col) = z;
    }
    return;
  }

  __shared__ char smem[98304];              // 2 x (As 16K + Bs 32K)
  int lane = tid & 63, quad = lane >> 4, l15 = lane & 15;
  int wave = tid >> 6;
  int wm = wave >> 2, wn = wave & 3;        // 2M x 4N
  int chb = (quad ^ (l15 & 7)) << 4;

  f32x4 acc[4][4] = {};

  stage_tile<128, K, 512>(A, row0, 0, smem);
  stage_tile<256, K, 512>(B, col0, 0, smem + 16384);

  constexpr int NT = K >> 6;                // 64 k-steps
  for (int t = 0; t < NT; ++t) {
    char* buf = smem + (t & 1) * 49152;
    if (t + 1 < NT) {
      char* nbuf = smem + ((t + 1) & 1) * 49152;
      int kn = (t + 1) << 6;
      stage_tile<128, K, 512>(A, row0, kn, nbuf);
      stage_tile<256, K, 512>(B, col0, kn, nbuf + 16384);
      asm volatile("s_waitcnt vmcnt(6)" ::: "memory");   // tile t done; t+1 in flight
    } else {
      asm volatile("s_waitcnt vmcnt(0)" ::: "memory");
    }
    __builtin_amdgcn_s_barrier();
    char* As = buf;
    char* Bs = buf + 16384;
    __builtin_amdgcn_s_setprio(1);
#pragma unroll
    for (int kk = 0; kk < 2; ++kk) {
      int xo = chb ^ (kk << 6);
      bf16x8 af[4], bg[4];
#pragma unroll
      for (int mt = 0; mt < 4; ++mt)
        af[mt] = *(const bf16x8*)(As + (wm * 64 + mt * 16 + l15) * 128 + xo);
#pragma unroll
      for (int nf = 0; nf < 4; ++nf)
        bg[nf] = *(const bf16x8*)(Bs + (wn * 64 + nf * 16 + l15) * 128 + xo);
#pragma unroll
      for (int mt = 0; mt < 4; ++mt)
#pragma unroll
        for (int nf = 0; nf < 4; ++nf)
          acc[mt][nf] = __builtin_amdgcn_mfma_f32_16x16x32_bf16(
              bg[nf], af[mt], acc[mt][nf], 0, 0, 0);   // swapped: rows=d
    }
    __builtin_amdgcn_s_setprio(0);
    __builtin_amdgcn_s_barrier();
  }

  // Swapped epilogue: lane holds d = d_base+nf*16+quad*4+r (contig), one row
  // index t per mt. float4 bias + float4 store; dout is a multiple of 128 so
  // one compare covers the 4 packed cols.
  int p_base = row0 + wm * 64;
  int d_base = col0 + wn * 64;
  float4 bv[4];
#pragma unroll
  for (int nf = 0; nf < 4; ++nf)
    bv[nf] = *(const float4*)(bias + d_base + nf * 16 + quad * 4);
#pragma unroll
  for (int mt = 0; mt < 4; ++mt) {
    int m2 = rowtok[p_base + mt * 16 + l15];
    int t = m2 & 0x3FFF;
    int dout = 128 << (m2 >> 14);
#pragma unroll
    for (int nf = 0; nf < 4; ++nf) {
      int d0 = d_base + nf * 16 + quad * 4;
      bool ok = d0 < dout;
      float4 o;
      o.x = ok ? acc[mt][nf][0] + bv[nf].x : 0.0f;
      o.y = ok ? acc[mt][nf][1] + bv[nf].y : 0.0f;
      o.z = ok ? acc[mt][nf][2] + bv[nf].z : 0.0f;
      o.w = ok ? acc[mt][nf][3] + bv[nf].w : 0.0f;
      *(float4*)(out + (size_t)t * N + d0) = o;
    }
  }
}

extern "C" void kernel_launch(void* const* d_in, const int* in_sizes, int n_in,
                              void* d_out, int out_size, void* d_ws, size_t ws_size,
                              hipStream_t stream) {
  const float* x  = (const float*)d_in[0];
  const float* w1 = (const float*)d_in[1];
  const float* b1 = (const float*)d_in[2];
  const float* w2 = (const float*)d_in[3];
  const float* b2 = (const float*)d_in[4];
  const int*   tm = (const int*)d_in[5];
  float* out = (float*)d_out;

  char* ws = (char*)d_ws;
  int* meta = (int*)ws;                                     // 128 KB reserved
  unsigned short* xb  = (unsigned short*)(ws + 131072);     // 32 MB
  unsigned short* w1b = (unsigned short*)(ws + 33685504);   //  8 MB
  unsigned short* w2b = (unsigned short*)(ws + 42074112);   //  8 MB
  unsigned short* hb  = (unsigned short*)(ws + 50462720);   // 128 MB (176.125 MB)

  sortw_kernel<<<2049, 1024, 0, stream>>>(tm, w1, w2, meta, w1b, w2b);
  prepx_kernel<<<M_TOK, 256, 0, stream>>>(x, meta, xb);
  gemm1_kernel<<<4096, 256, 0, stream>>>(xb, w1b, b1, meta, hb);
  gemm2_kernel<<<512, 512, 0, stream>>>(hb, w2b, b2, meta, out);
}

// Round 12
// 302.609 us; speedup vs baseline: 1.2071x; 1.2071x over previous
//
#include <hip/hip_runtime.h>
#include <hip/hip_bf16.h>

// NestedFeedForward: x[16384,1024] fp32, w1[4096,1024], b1[4096], w2[1024,4096],
// b2[1024], token_mask[16384] in [0,4).   d(t) = 128 << mask[t]
//   h = gelu( mask_in(x) @ w1^T + b1 )   (hidden always full 4096)
//   y = mask_out( h @ w2^T + b2 )
// Round 16: exact revert to the R6 configuration (302.7us measured) after
// R7-R11 structural experiments all regressed or nulled:
//  - 256x256 gemm1: 3x VGPR-clamp spill (104/56 VGPR vs 128 needed)
//  - 128x256 gemm2: 1 block/CU occupancy collapse (144us, VALUBusy 9.6%)
//  - XCD-chunked gemm1: null (L3 theory wrong)
// gemm1 128x128 @ 631 TF = the 2-phase stage->bar->MFMA->bar structural
// ceiling (matches learn_hip m230/m233); escape requires the 8-phase
// schedule, out of budget here.

typedef __bf16 bf16x8 __attribute__((ext_vector_type(8)));
typedef float f32x4 __attribute__((ext_vector_type(4)));

#define M_TOK   16384
#define DIM     1024
#define HID     4096

// meta (ints at ws+0): [40..47] per-XCD compute count T_k, [64..191] kmax per
// 128-row block (also strip colblock count = kmax/128), [256..1279] gemm2 map
// (8 XCD chunks x 128), [2560..18943] rowtok.
#define META_TK    40
#define META_BLK   64
#define META_MAP   256
#define META_RT    2560

__device__ inline unsigned int pk_bf16(float a, float b) {
  unsigned int r;
  asm("v_cvt_pk_bf16_f32 %0, %1, %2" : "=v"(r) : "v"(a), "v"(b));
  return r;
}

// tanh-form gelu: v * rcp(1 + exp2(-(c1*v + c2*v^3))), c1 = 2*0.79788456*log2e
// max |delta| vs erf-gelu ~1e-3, below the bf16 h-storage error.
__device__ inline float gelu_f(float v) {
  float v2 = v * v;
  float w = v * fmaf(0.10294324f, v2, 2.30220830f);
  float e = __builtin_amdgcn_exp2f(-w);
  return v * __builtin_amdgcn_rcpf(1.0f + e);
}

__device__ inline void async_copy16(const void* g, void* s) {
  __builtin_amdgcn_global_load_lds(
      (const __attribute__((address_space(1))) unsigned int*)g,
      (__attribute__((address_space(3))) unsigned int*)s,
      16, 0, 0);
}

// Stage a ROWS x 64-col bf16 tile into LDS with XOR chunk swizzle (2-way
// aliasing on the b128 readbacks = free, m136).  ROWS=128 -> 4 loads/thread.
template<int ROWS, int LDK>
__device__ inline void stage_tile(const unsigned short* __restrict__ g,
                                  int row0, int k0, char* lds) {
  const char* gbase = (const char*)g;
  int tid = threadIdx.x;
#pragma unroll
  for (int i = 0; i < ROWS / 32; ++i) {
    int q = i * 256 + tid;          // ROWS*8 chunks of 16B
    int r = q >> 3;                 // tile row
    int c = q & 7;                  // LDS chunk within row
    int gc = c ^ (r & 7);           // swizzled source chunk
    const void* gp = gbase + ((size_t)(row0 + r) * LDK + (size_t)k0 + gc * 8) * 2;
    async_copy16(gp, lds + (size_t)q * 16);
  }
}

// -------- fused: block 0 = sort + metadata; blocks 1.. = w1/w2 -> bf16 -----
__global__ __launch_bounds__(1024) void sortw_kernel(
    const int* __restrict__ tm,
    const float* __restrict__ w1,
    const float* __restrict__ w2,
    int* __restrict__ meta,
    unsigned short* __restrict__ w1b,
    unsigned short* __restrict__ w2b) {
  int tid = threadIdx.x;
  if (blockIdx.x != 0) {
    // weight conversion: independent of the sort, fills the idle CUs
    size_t i = (size_t)(blockIdx.x - 1) * 4096 + tid * 4;   // 0 .. 8388607
    const float* src;
    unsigned short* dst;
    if (i < (size_t)HID * DIM) { src = w1; dst = w1b; }
    else { src = w2 - (size_t)HID * DIM; dst = w2b - (size_t)HID * DIM; }
    float4 v = *(const float4*)(src + i);
    uint2 o;
    o.x = pk_bf16(v.x, v.y);
    o.y = pk_bf16(v.z, v.w);
    *(uint2*)(dst + i) = o;
    return;
  }

  // ---------------- block 0: counting sort of 16384 tokens ----------------
  __shared__ unsigned short rt[16384];      // 32 KB sorted (t | e<<14) u16
  __shared__ unsigned int w01[16], w23[16]; // per-wave packed count totals
  __shared__ int sbase[4];
  __shared__ int cb[128];
  int lane = tid & 63, wv = tid >> 6;

  int c0 = 0, c1 = 0, c2 = 0, c3 = 0;
  unsigned int epack = 0;
  int4 tv[4];
#pragma unroll
  for (int j = 0; j < 4; ++j)
    tv[j] = *(const int4*)(tm + tid * 16 + j * 4);
#pragma unroll
  for (int j = 0; j < 4; ++j) {
    int e;
    e = tv[j].x; epack |= (unsigned)e << (2 * (4 * j + 0)); c0 += (e == 0); c1 += (e == 1); c2 += (e == 2); c3 += (e == 3);
    e = tv[j].y; epack |= (unsigned)e << (2 * (4 * j + 1)); c0 += (e == 0); c1 += (e == 1); c2 += (e == 2); c3 += (e == 3);
    e = tv[j].z; epack |= (unsigned)e << (2 * (4 * j + 2)); c0 += (e == 0); c1 += (e == 1); c2 += (e == 2); c3 += (e == 3);
    e = tv[j].w; epack |= (unsigned)e << (2 * (4 * j + 3)); c0 += (e == 0); c1 += (e == 1); c2 += (e == 2); c3 += (e == 3);
  }
  // hierarchical exclusive scan of (c0,c1) and (c2,c3), 16-bit packed:
  // intra-wave max 64*16=1024, grand total max 16384 -- both fit 16 bits.
  unsigned int p01 = (unsigned)c0 | ((unsigned)c1 << 16);
  unsigned int p23 = (unsigned)c2 | ((unsigned)c3 << 16);
  unsigned int i01 = p01, i23 = p23;
#pragma unroll
  for (int s = 1; s < 64; s <<= 1) {
    unsigned int t0 = __shfl_up(i01, s, 64);
    unsigned int t1 = __shfl_up(i23, s, 64);
    if (lane >= s) { i01 += t0; i23 += t1; }
  }
  if (lane == 63) { w01[wv] = i01; w23[wv] = i23; }
  unsigned int e01 = i01 - p01, e23 = i23 - p23;   // lane-exclusive prefixes
  __syncthreads();
  if (tid < 16) {
    unsigned int a = w01[tid], b = w23[tid];
    unsigned int ia = a, ib = b;
#pragma unroll
    for (int s = 1; s < 16; s <<= 1) {
      unsigned int t0 = __shfl_up(ia, s, 64);
      unsigned int t1 = __shfl_up(ib, s, 64);
      if (tid >= s) { ia += t0; ib += t1; }
    }
    w01[tid] = ia - a;                       // exclusive wave offsets
    w23[tid] = ib - b;
    if (tid == 15) {
      int t0 = (int)(ia & 0xFFFF), t1 = (int)(ia >> 16), t2 = (int)(ib & 0xFFFF);
      sbase[0] = 0; sbase[1] = t0; sbase[2] = t0 + t1; sbase[3] = t0 + t1 + t2;
    }
  }
  __syncthreads();
  int off0 = sbase[0] + (int)((w01[wv] & 0xFFFF) + (e01 & 0xFFFF));
  int off1 = sbase[1] + (int)((w01[wv] >> 16) + (e01 >> 16));
  int off2 = sbase[2] + (int)((w23[wv] & 0xFFFF) + (e23 & 0xFFFF));
  int off3 = sbase[3] + (int)((w23[wv] >> 16) + (e23 >> 16));
#pragma unroll
  for (int j = 0; j < 16; ++j) {
    int e = (epack >> (2 * j)) & 3;
    int t = tid * 16 + j;
    int pos = (e == 0) ? off0++ : (e == 1) ? off1++ : (e == 2) ? off2++ : off3++;
    rt[pos] = (unsigned short)(t | (e << 14));     // LDS scatter, not global
  }
  __syncthreads();

  // 128-row strip metadata (kmax for gemm1 / colblock count for gemm2)
  if (tid < 128) {
    int last = tid * 128 + 127;
    int e = (last >= sbase[1]) + (last >= sbase[2]) + (last >= sbase[3]);
    cb[tid] = 1 << e;
    meta[META_BLK + tid] = 128 << e;
  }
  __syncthreads();
  // per-XCD gemm2 map: XCD k owns strips {s : s%8==k} (16 strips, balanced
  // since strips stride uniformly across the sorted expert bands). Compute
  // blocks first, zeros after, threshold T_k.
  if (tid < 8) {
    int k = tid;
    int* map = meta + META_MAP + k * 128;
    int Tk = 0;
    for (int j = 0; j < 16; ++j) Tk += cb[k + 8 * j];
    meta[META_TK + k] = Tk;
    int pos = 0, zpos = Tk;
    for (int j = 0; j < 16; ++j) {
      int s = k + 8 * j;
      int n = cb[s];
      for (int c = 0; c < n; ++c) map[pos++] = s * 8 + c;
      for (int c = n; c < 8; ++c) map[zpos++] = s * 8 + c;
    }
  }
  // coalesced rowtok dump (u16 -> int)
  int* rowtok = meta + META_RT;
#pragma unroll
  for (int j = 0; j < 16; ++j)
    rowtok[j * 1024 + tid] = (int)rt[j * 1024 + tid];
}

// ---------------- prep: cvt_x (permuted gather) -> bf16 --------------------
// Partial IO: read x only d < din, write xb only d < kmax(block); gemm1 never
// touches A beyond kmax so the padding bytes were pure HBM waste.
__global__ void prepx_kernel(const float* __restrict__ x,
                             const int* __restrict__ meta,
                             unsigned short* __restrict__ xb) {
  int b = blockIdx.x;
  int tid = threadIdx.x;
  int mt = meta[META_RT + b];
  int t = mt & 0x3FFF;
  int din = 128 << (mt >> 14);
  int kb = meta[META_BLK + (b >> 7)];       // kmax >= din (sorted rows)
  int d = tid * 4;
  if (d < kb) {
    uint2 o; o.x = 0; o.y = 0;
    if (d < din) {                          // din multiple of 128: uniform
      float4 v = *(const float4*)(x + (size_t)t * DIM + d);
      o.x = pk_bf16(v.x, v.y);
      o.y = pk_bf16(v.z, v.w);
    }
    *(uint2*)(xb + (size_t)b * DIM + d) = o;
  }
}

// ---- GEMM1: hb[pos,f] = gelu( xb[pos,:] . w1b[f,:] + b1[f] ), bf16 out ----
// Double-buffered + counted vmcnt: stage(t+1) issued, vmcnt(8) waits only for
// tile t's 8 loads; t+1's loads stay in flight across both raw barriers.
__global__ __launch_bounds__(256) void gemm1_kernel(
    const unsigned short* __restrict__ A,   // xb [16384,1024] bf16 (permuted)
    const unsigned short* __restrict__ B,   // w1b [4096,1024] bf16
    const float* __restrict__ bias,         // b1 [4096]
    const int* __restrict__ meta,
    unsigned short* __restrict__ H)         // hb [16384,4096] bf16 (permuted)
{
  constexpr int K = DIM, N = HID;
  __shared__ char smem[65536];              // 2 x (As 16K + Bs 16K)
  int tid = threadIdx.x;
  int lane = tid & 63, quad = lane >> 4, l15 = lane & 15;
  int wave = tid >> 6, wm = wave & 1, wn = wave >> 1;
  int rowblk = 127 - (blockIdx.x >> 5);
  int row0 = rowblk * 128, col0 = (blockIdx.x & 31) * 128;
  int kmax = meta[META_BLK + rowblk];

  int chb = (quad ^ (l15 & 7)) << 4;        // staging swizzle base

  f32x4 acc[4][4] = {};

  stage_tile<128, K>(A, row0, 0, smem);
  stage_tile<128, K>(B, col0, 0, smem + 16384);

  int nt = kmax >> 6;
  for (int t = 0; t < nt; ++t) {
    char* buf = smem + ((t & 1) << 15);
    if (t + 1 < nt) {                       // prefetch into the other buffer
      char* nbuf = smem + (((t + 1) & 1) << 15);
      int kn = (t + 1) << 6;
      stage_tile<128, K>(A, row0, kn, nbuf);
      stage_tile<128, K>(B, col0, kn, nbuf + 16384);
      asm volatile("s_waitcnt vmcnt(8)" ::: "memory");   // tile t done; t+1 in flight
    } else {
      asm volatile("s_waitcnt vmcnt(0)" ::: "memory");
    }
    __builtin_amdgcn_s_barrier();           // all waves' tile-t LDS writes visible
    char* As = buf;
    char* Bs = buf + 16384;
#pragma unroll
    for (int kk = 0; kk < 2; ++kk) {
      int xo = chb ^ (kk << 6);
      bf16x8 af[4], bg[4];
#pragma unroll
      for (int mt = 0; mt < 4; ++mt)
        af[mt] = *(const bf16x8*)(As + (wm * 64 + mt * 16 + l15) * 128 + xo);
#pragma unroll
      for (int nt2 = 0; nt2 < 4; ++nt2)
        bg[nt2] = *(const bf16x8*)(Bs + (wn * 64 + nt2 * 16 + l15) * 128 + xo);
#pragma unroll
      for (int mt = 0; mt < 4; ++mt)
#pragma unroll
        for (int nt2 = 0; nt2 < 4; ++nt2)
          acc[mt][nt2] = __builtin_amdgcn_mfma_f32_16x16x32_bf16(
              bg[nt2], af[mt], acc[mt][nt2], 0, 0, 0);   // swapped: rows=f
    }
    __builtin_amdgcn_s_barrier();           // reads of buf[t] done before t+2 overwrites
  }

  // Swapped epilogue: lane holds f = f_base+nt*16+quad*4+r (r=0..3 contig),
  // t = t_base+mt*16+l15. Pack 4 accs -> uint2, one 8B store each.
  int t_base = row0 + wm * 64;
  int f_base = col0 + wn * 64;
#pragma unroll
  for (int nt2 = 0; nt2 < 4; ++nt2) {
    int f0 = f_base + nt2 * 16 + quad * 4;
    float4 bv = *(const float4*)(bias + f0);
#pragma unroll
    for (int mt = 0; mt < 4; ++mt) {
      int t = t_base + mt * 16 + l15;
      float v0 = gelu_f(acc[mt][nt2][0] + bv.x);
      float v1 = gelu_f(acc[mt][nt2][1] + bv.y);
      float v2 = gelu_f(acc[mt][nt2][2] + bv.z);
      float v3 = gelu_f(acc[mt][nt2][3] + bv.w);
      uint2 p;
      p.x = pk_bf16(v0, v1);
      p.y = pk_bf16(v2, v3);
      *(uint2*)(H + (size_t)t * N + f0) = p;
    }
  }
}

// ---- GEMM2: 128x128 tiles, XCD-chunked schedule, dbuf + counted vmcnt ----
// XCD k (= blockIdx&7) walks its own map chunk in order: same-strip colblocks
// run consecutively on one XCD -> hb A-panel chunks stay hot in its L2.
__global__ __launch_bounds__(256) void gemm2_kernel(
    const unsigned short* __restrict__ A,   // hb [16384,4096] bf16 (permuted)
    const unsigned short* __restrict__ B,   // w2b [1024,4096] bf16
    const float* __restrict__ bias,         // b2 [1024]
    const int* __restrict__ meta,
    float* __restrict__ out)                // [16384,1024] fp32
{
  constexpr int K = HID, N = DIM;
  int Bk = blockIdx.x & 7, ord = blockIdx.x >> 3;
  int Tk = meta[META_TK + Bk];
  int mp = meta[META_MAP + Bk * 128 + ord];
  int row0 = (mp >> 3) * 128, col0 = (mp & 7) * 128;
  const int* rowtok = meta + META_RT;
  int tid = threadIdx.x;

  if (ord >= Tk) {
    // every row in this strip has dout <= col0: coalesced zeros
    float4 z = make_float4(0.f, 0.f, 0.f, 0.f);
#pragma unroll
    for (int i = 0; i < 16; ++i) {
      int idx = i * 256 + tid;              // 4096 float4 = 128x128 tile
      int r = idx >> 5;
      int col = (idx & 31) * 4;
      int t = rowtok[row0 + r] & 0x3FFF;
      *(float4*)(out + (size_t)t * N + col0 + col) = z;
    }
    return;
  }

  __shared__ char smem[65536];              // 2 x (As 16K + Bs 16K)
  int lane = tid & 63, quad = lane >> 4, l15 = lane & 15;
  int wave = tid >> 6, wm = wave & 1, wn = wave >> 1;
  int chb = (quad ^ (l15 & 7)) << 4;

  f32x4 acc[4][4] = {};

  stage_tile<128, K>(A, row0, 0, smem);
  stage_tile<128, K>(B, col0, 0, smem + 16384);

  constexpr int NT = K >> 6;                // 64 k-steps
  for (int t = 0; t < NT; ++t) {
    char* buf = smem + ((t & 1) << 15);
    if (t + 1 < NT) {
      char* nbuf = smem + (((t + 1) & 1) << 15);
      int kn = (t + 1) << 6;
      stage_tile<128, K>(A, row0, kn, nbuf);
      stage_tile<128, K>(B, col0, kn, nbuf + 16384);
      asm volatile("s_waitcnt vmcnt(8)" ::: "memory");
    } else {
      asm volatile("s_waitcnt vmcnt(0)" ::: "memory");
    }
    __builtin_amdgcn_s_barrier();
    char* As = buf;
    char* Bs = buf + 16384;
#pragma unroll
    for (int kk = 0; kk < 2; ++kk) {
      int xo = chb ^ (kk << 6);
      bf16x8 af[4], bg[4];
#pragma unroll
      for (int mt = 0; mt < 4; ++mt)
        af[mt] = *(const bf16x8*)(As + (wm * 64 + mt * 16 + l15) * 128 + xo);
#pragma unroll
      for (int nt2 = 0; nt2 < 4; ++nt2)
        bg[nt2] = *(const bf16x8*)(Bs + (wn * 64 + nt2 * 16 + l15) * 128 + xo);
#pragma unroll
      for (int mt = 0; mt < 4; ++mt)
#pragma unroll
        for (int nt2 = 0; nt2 < 4; ++nt2)
          acc[mt][nt2] = __builtin_amdgcn_mfma_f32_16x16x32_bf16(
              bg[nt2], af[mt], acc[mt][nt2], 0, 0, 0);   // swapped: rows=d
    }
    __builtin_amdgcn_s_barrier();
  }

  // Swapped epilogue: lane holds d = d_base+nt*16+quad*4+r (contig), one row
  // index t per mt. float4 bias + float4 store; dout is a multiple of 128 so
  // one compare covers the 4 packed cols.
  int p_base = row0 + wm * 64;
  int d_base = col0 + wn * 64;
  float4 bv[4];
#pragma unroll
  for (int nt2 = 0; nt2 < 4; ++nt2)
    bv[nt2] = *(const float4*)(bias + d_base + nt2 * 16 + quad * 4);
#pragma unroll
  for (int mt = 0; mt < 4; ++mt) {
    int m2 = rowtok[p_base + mt * 16 + l15];
    int t = m2 & 0x3FFF;
    int dout = 128 << (m2 >> 14);
#pragma unroll
    for (int nt2 = 0; nt2 < 4; ++nt2) {
      int d0 = d_base + nt2 * 16 + quad * 4;
      bool ok = d0 < dout;
      float4 o;
      o.x = ok ? acc[mt][nt2][0] + bv[nt2].x : 0.0f;
      o.y = ok ? acc[mt][nt2][1] + bv[nt2].y : 0.0f;
      o.z = ok ? acc[mt][nt2][2] + bv[nt2].z : 0.0f;
      o.w = ok ? acc[mt][nt2][3] + bv[nt2].w : 0.0f;
      *(float4*)(out + (size_t)t * N + d0) = o;
    }
  }
}

extern "C" void kernel_launch(void* const* d_in, const int* in_sizes, int n_in,
                              void* d_out, int out_size, void* d_ws, size_t ws_size,
                              hipStream_t stream) {
  const float* x  = (const float*)d_in[0];
  const float* w1 = (const float*)d_in[1];
  const float* b1 = (const float*)d_in[2];
  const float* w2 = (const float*)d_in[3];
  const float* b2 = (const float*)d_in[4];
  const int*   tm = (const int*)d_in[5];
  float* out = (float*)d_out;

  char* ws = (char*)d_ws;
  int* meta = (int*)ws;                                     // 128 KB reserved
  unsigned short* xb  = (unsigned short*)(ws + 131072);     // 32 MB
  unsigned short* w1b = (unsigned short*)(ws + 33685504);   //  8 MB
  unsigned short* w2b = (unsigned short*)(ws + 42074112);   //  8 MB
  unsigned short* hb  = (unsigned short*)(ws + 50462720);   // 128 MB (176.125 MB)

  sortw_kernel<<<2049, 1024, 0, stream>>>(tm, w1, w2, meta, w1b, w2b);
  prepx_kernel<<<M_TOK, 256, 0, stream>>>(x, meta, xb);
  gemm1_kernel<<<4096, 256, 0, stream>>>(xb, w1b, b1, meta, hb);
  gemm2_kernel<<<1024, 256, 0, stream>>>(hb, w2b, b2, meta, out);
}